// Round 2
// baseline (330.910 us; speedup 1.0000x reference)
//
#include <hip/hip_runtime.h>

typedef __bf16 bf16;
typedef __bf16 bf16x8 __attribute__((ext_vector_type(8)));
typedef float f32x4 __attribute__((ext_vector_type(4)));

__device__ __forceinline__ void gll16(const void* g, void* l) {
    __builtin_amdgcn_global_load_lds((const __attribute__((address_space(1))) void*)g,
                                     (__attribute__((address_space(3))) void*)l, 16, 0, 0);
}

// ---------------- weight transpose + fp32->bf16: in[R][C] f32 -> out[C][R] bf16 ----------------
__launch_bounds__(256)
__global__ void transpose_k(const float* __restrict__ in, bf16* __restrict__ out, int R, int Cc) {
    __shared__ float tl[32][33];
    const int c0 = blockIdx.x * 32, r0 = blockIdx.y * 32;
    const int cl = threadIdx.x & 31, r8 = threadIdx.x >> 5;
#pragma unroll
    for (int k = 0; k < 4; k++) {
        int r = k * 8 + r8;
        tl[r][cl] = in[(size_t)(r0 + r) * Cc + c0 + cl];
    }
    __syncthreads();
#pragma unroll
    for (int k = 0; k < 4; k++) {
        int cc = k * 8 + r8;
        out[(size_t)(c0 + cc) * R + r0 + cl] = (bf16)tl[cl][cc];
    }
}

// ---------------- dual LayerNorm: x[B,C,n] f32 -> a[B,n,C] bf16, f[B,n,C] bf16 ----------------
// LN stats (mean/var over C) are shared by both branches; only g,b differ.
__launch_bounds__(256)
__global__ void ln_kernel(const float* __restrict__ x,
                          const float* __restrict__ g1, const float* __restrict__ b1,
                          const float* __restrict__ g2, const float* __restrict__ b2,
                          bf16* __restrict__ a, bf16* __restrict__ f) {
    const int tid = threadIdx.x;
    const int bb = blockIdx.x >> 2;
    const int ic = blockIdx.x & 3;
    const int io = tid & 63, cp = tid >> 6;
    const int i = ic * 64 + io;
    const size_t xbase = (size_t)bb * 384 * 256 + i;
    float s = 0.f, ss = 0.f;
#pragma unroll 4
    for (int j = 0; j < 96; j++) {
        int c = cp * 96 + j;
        float v = x[xbase + (size_t)c * 256];
        s += v; ss += v * v;
    }
    __shared__ float S[4][64], SS[4][64], Mn[64], Rs[64];
    S[cp][io] = s; SS[cp][io] = ss;
    __syncthreads();
    if (tid < 64) {
        float t1 = S[0][tid] + S[1][tid] + S[2][tid] + S[3][tid];
        float t2 = SS[0][tid] + SS[1][tid] + SS[2][tid] + SS[3][tid];
        float mean = t1 * (1.0f / 384.0f);
        float var  = t2 * (1.0f / 384.0f) - mean * mean;
        Mn[tid] = mean;
        Rs[tid] = rsqrtf(var + 1e-5f);
    }
    __syncthreads();
    const float mean = Mn[io], rstd = Rs[io];
    const size_t orow = ((size_t)bb * 256 + i) * 384;
#pragma unroll 4
    for (int j = 0; j < 96; j++) {
        int c = cp * 96 + j;
        float v = x[xbase + (size_t)c * 256];
        float nh = (v - mean) * rstd;
        a[orow + c] = (bf16)(nh * g1[c] + b1[c]);
        f[orow + c] = (bf16)(nh * g2[c] + b2[c]);
    }
}

// ---------------- GEMM: C[M,N] = A[M,K] @ Bt[N,K]^T (+bias)(+gelu) ----------------
// 128x128 tile, BK=32, 4 waves, each wave 64x64 (4x4 MFMA 16x16x32 tiles).
// EPI: 0 = none, 1 = +bias, 2 = +bias +exact gelu. bias is fp32.
template <int EPI>
__launch_bounds__(256)
__global__ void gemm_bt(const bf16* __restrict__ A, const bf16* __restrict__ Bt,
                        const float* __restrict__ bias, bf16* __restrict__ C,
                        int M, int N, int K) {
    __shared__ bf16 lA[128 * 32];
    __shared__ bf16 lB[128 * 32];
    const int tid = threadIdx.x;
    const int m0 = blockIdx.y * 128;
    const int n0 = blockIdx.x * 128;
    const int lane = tid & 63, w = tid >> 6;
    const int l16 = lane & 15, quad = lane >> 4;
    const int wm = (w & 1) * 64, wn = (w >> 1) * 64;

    f32x4 zero = {0.f, 0.f, 0.f, 0.f};
    f32x4 acc[4][4];
#pragma unroll
    for (int i = 0; i < 4; i++)
#pragma unroll
        for (int j = 0; j < 4; j++) acc[i][j] = zero;

    // staging chunks: 512 x 16B per tile; thread handles chunk tid and tid+256.
    // global_load_lds semantics: LDS dest = first-lane base + lane*16 — our per-lane
    // pointers are exactly contiguous-in-lane, so this matches.
    const int c0 = tid, c1 = tid + 256;
    const int r0 = c0 >> 2, k0c = (c0 & 3) * 8;
    const int r1 = c1 >> 2, k1c = (c1 & 3) * 8;
    const bf16* Abase = A + (size_t)m0 * K;
    const bf16* Bbase = Bt + (size_t)n0 * K;

    for (int kb = 0; kb < K; kb += 32) {
        gll16(Abase + (size_t)r0 * K + kb + k0c, lA + c0 * 8);
        gll16(Abase + (size_t)r1 * K + kb + k1c, lA + c1 * 8);
        gll16(Bbase + (size_t)r0 * K + kb + k0c, lB + c0 * 8);
        gll16(Bbase + (size_t)r1 * K + kb + k1c, lB + c1 * 8);
        __syncthreads();
        bf16x8 af[4], bfr[4];
#pragma unroll
        for (int i = 0; i < 4; i++)
            af[i] = *(const bf16x8*)(lA + (wm + i * 16 + l16) * 32 + quad * 8);
#pragma unroll
        for (int j = 0; j < 4; j++)
            bfr[j] = *(const bf16x8*)(lB + (wn + j * 16 + l16) * 32 + quad * 8);
#pragma unroll
        for (int i = 0; i < 4; i++)
#pragma unroll
            for (int j = 0; j < 4; j++)
                acc[i][j] = __builtin_amdgcn_mfma_f32_16x16x32_bf16(af[i], bfr[j], acc[i][j], 0, 0, 0);
        __syncthreads();
    }

#pragma unroll
    for (int j = 0; j < 4; j++) {
        const int col = n0 + wn + j * 16 + l16;
        float bv = 0.f;
        if (EPI >= 1) bv = bias[col];
#pragma unroll
        for (int i = 0; i < 4; i++) {
            const int rowb = m0 + wm + i * 16 + quad * 4;
#pragma unroll
            for (int r = 0; r < 4; r++) {
                float v = acc[i][j][r] + bv;
                if (EPI == 2) v = 0.5f * v * (1.0f + erff(v * 0.70710678118654752f));
                C[(size_t)(rowb + r) * N + col] = (bf16)v;
            }
        }
    }
}

// ---------------- fused attention per (b, h, 64-row q-chunk) ----------------
// qkv[16384][768] bf16: q at col h*32, k at 256+h*32, v at 512+h*32. btab fp32 [961][8].
__launch_bounds__(256)
__global__ void attn_kernel(const bf16* __restrict__ qkv,
                            const float* __restrict__ btab,
                            bf16* __restrict__ o) {
    __shared__ float sbias[961];
    __shared__ __align__(16) bf16 sVt[32][264];      // Vt[d][k]
    __shared__ __align__(16) bf16 sP[4][16][264];    // per-wave P chunk [16 q][256 k]
    const int tid = threadIdx.x;
    const int qc = blockIdx.x & 3;
    const int h  = (blockIdx.x >> 2) & 7;
    const int bb = blockIdx.x >> 5;
    const int lane = tid & 63, w = tid >> 6;
    const int l16 = lane & 15, quad = lane >> 4;
    const size_t qkvb = (size_t)bb * 256 * 768;

    for (int e = tid; e < 961; e += 256) sbias[e] = btab[e * 8 + h];
#pragma unroll
    for (int it = 0; it < 32; it++) {
        int e = it * 256 + tid;
        int k = e >> 5, d = e & 31;
        sVt[d][k] = qkv[qkvb + (size_t)k * 768 + 512 + h * 32 + d];
    }
    __syncthreads();

    const int qbase = qc * 64 + w * 16;
    // S = Q K^T : A-frag from Q rows, B-frag from K rows (gemm_bt form, K-depth 32)
    bf16x8 qf = *(const bf16x8*)(qkv + qkvb + (size_t)(qbase + l16) * 768 + h * 32 + quad * 8);
    f32x4 zero = {0.f, 0.f, 0.f, 0.f};
    f32x4 s[16];
#pragma unroll
    for (int kt = 0; kt < 16; kt++) {
        bf16x8 kf = *(const bf16x8*)(qkv + qkvb + (size_t)(kt * 16 + l16) * 768 + 256 + h * 32 + quad * 8);
        s[kt] = __builtin_amdgcn_mfma_f32_16x16x32_bf16(qf, kf, zero, 0, 0, 0);
    }
    // scale + relative bias; track row max (lane holds rows quad*4+r, cols kt*16+l16)
    const int qi0 = qbase + quad * 4;
    float mx[4] = {-1e30f, -1e30f, -1e30f, -1e30f};
#pragma unroll
    for (int kt = 0; kt < 16; kt++) {
        const int j = kt * 16 + l16;
        const int yj = j >> 4, xj = j & 15;
#pragma unroll
        for (int r = 0; r < 4; r++) {
            const int q = qi0 + r;
            const int tix = ((q >> 4) - yj + 15) * 31 + ((q & 15) - xj + 15);
            float v = s[kt][r] * 0.17677669529663687f + sbias[tix];
            s[kt][r] = v;
            mx[r] = fmaxf(mx[r], v);
        }
    }
#pragma unroll
    for (int r = 0; r < 4; r++)
        for (int msk = 1; msk < 16; msk <<= 1)
            mx[r] = fmaxf(mx[r], __shfl_xor(mx[r], msk, 64));
    float sum[4] = {0.f, 0.f, 0.f, 0.f};
#pragma unroll
    for (int kt = 0; kt < 16; kt++)
#pragma unroll
        for (int r = 0; r < 4; r++) {
            float e = __expf(s[kt][r] - mx[r]);
            s[kt][r] = e;
            sum[r] += e;
        }
#pragma unroll
    for (int r = 0; r < 4; r++) {
        for (int msk = 1; msk < 16; msk <<= 1)
            sum[r] += __shfl_xor(sum[r], msk, 64);
        sum[r] = 1.0f / sum[r];
    }
    // P (C-layout) -> LDS -> A-layout for PV (wave-local round-trip)
#pragma unroll
    for (int kt = 0; kt < 16; kt++)
#pragma unroll
        for (int r = 0; r < 4; r++)
            sP[w][quad * 4 + r][kt * 16 + l16] = (bf16)(s[kt][r] * sum[r]);
    f32x4 oacc[2];
    oacc[0] = zero; oacc[1] = zero;
#pragma unroll
    for (int ks = 0; ks < 8; ks++) {
        bf16x8 pf = *(const bf16x8*)(&sP[w][l16][ks * 32 + quad * 8]);
#pragma unroll
        for (int dt = 0; dt < 2; dt++) {
            bf16x8 vf = *(const bf16x8*)(&sVt[dt * 16 + l16][ks * 32 + quad * 8]);
            oacc[dt] = __builtin_amdgcn_mfma_f32_16x16x32_bf16(pf, vf, oacc[dt], 0, 0, 0);
        }
    }
#pragma unroll
    for (int dt = 0; dt < 2; dt++)
#pragma unroll
        for (int r = 0; r < 4; r++)
            o[(size_t)(bb * 256 + qbase + quad * 4 + r) * 256 + h * 32 + dt * 16 + l16] = (bf16)oacc[dt][r];
}

// ---------------- final: out[b,c,i] = x[b,c,i] + attn[b,i,c] + ffo[b,i,c] (fp32 out) ---------
__launch_bounds__(256)
__global__ void final_add(const float* __restrict__ x, const bf16* __restrict__ attn,
                          const bf16* __restrict__ ffo, float* __restrict__ out) {
    __shared__ float tile[64][65];
    const int tid = threadIdx.x;
    const int i0 = (blockIdx.x & 3) * 64;
    const int c0 = ((blockIdx.x >> 2) % 6) * 64;
    const int bb = blockIdx.x / 24;
    const int cl = tid & 63, i8 = tid >> 6;
#pragma unroll
    for (int k = 0; k < 16; k++) {
        int il = k * 4 + i8;
        size_t addr = ((size_t)(bb * 256 + i0 + il)) * 384 + c0 + cl;
        tile[il][cl] = (float)attn[addr] + (float)ffo[addr];
    }
    __syncthreads();
    const int il2 = tid & 63, c8 = tid >> 6;
#pragma unroll
    for (int k = 0; k < 16; k++) {
        int cl2 = k * 4 + c8;
        size_t addr = ((size_t)(bb * 384 + c0 + cl2)) * 256 + i0 + il2;
        out[addr] = x[addr] + tile[il2][cl2];
    }
}

extern "C" void kernel_launch(void* const* d_in, const int* in_sizes, int n_in,
                              void* d_out, int out_size, void* d_ws, size_t ws_size,
                              hipStream_t stream) {
    const float* x    = (const float*)d_in[0];
    const float* g1   = (const float*)d_in[1];
    const float* b1   = (const float*)d_in[2];
    const float* wqkv = (const float*)d_in[3];
    const float* btab = (const float*)d_in[4];
    const float* wout = (const float*)d_in[5];
    const float* bout = (const float*)d_in[6];
    const float* g2   = (const float*)d_in[7];
    const float* b2   = (const float*)d_in[8];
    const float* wff1 = (const float*)d_in[9];
    const float* bff1 = (const float*)d_in[10];
    const float* wff2 = (const float*)d_in[11];
    const float* bff2 = (const float*)d_in[12];
    float* out = (float*)d_out;

    // workspace layout (bf16 elements). weights first, then long-lived buffers,
    // then one reuse region R for time-disjoint {a, qkv} -> {o} -> {ffh}.
    bf16* ws = (bf16*)d_ws;
    const size_t NA = 6291456;                 // 16384*384
    bf16* wqkvT = ws;                          // [768,384]
    bf16* woutT = wqkvT + 294912;              // [384,256]
    bf16* wff1T = woutT + 98304;               // [1536,384]
    bf16* wff2T = wff1T + 589824;              // [384,1536]
    bf16* f_buf    = ws + 1572864;             // [16384,384]
    bf16* attn_buf = f_buf + NA;               // [16384,384]
    bf16* ffo_buf  = attn_buf + NA;            // [16384,384]
    bf16* R        = ffo_buf + NA;             // reuse region, 25165824 elems
    bf16* a_buf    = R;                        // [16384,384]   live ln -> qkvgemm
    bf16* qkv_buf  = R + NA;                   // [16384,768]   live qkvgemm -> attn
    bf16* o_buf    = R;                        // [16384,256]   live attn -> outproj
    bf16* ffh_buf  = R;                        // [16384,1536]  live ff1 -> ff2
    // total: 1572864 + 3*6291456 + 25165824 = 45,613,056 bf16 = ~91.2 MB

    dim3 b256(256);
    transpose_k<<<dim3(24, 12), b256, 0, stream>>>(wqkv, wqkvT, 384, 768);
    transpose_k<<<dim3(12, 8),  b256, 0, stream>>>(wout, woutT, 256, 384);
    transpose_k<<<dim3(48, 12), b256, 0, stream>>>(wff1, wff1T, 384, 1536);
    transpose_k<<<dim3(12, 48), b256, 0, stream>>>(wff2, wff2T, 1536, 384);

    ln_kernel<<<256, b256, 0, stream>>>(x, g1, b1, g2, b2, a_buf, f_buf);

    gemm_bt<0><<<dim3(6, 128),  b256, 0, stream>>>(a_buf, wqkvT, nullptr, qkv_buf, 16384, 768, 384);
    attn_kernel<<<2048, b256, 0, stream>>>(qkv_buf, btab, o_buf);
    gemm_bt<1><<<dim3(3, 128),  b256, 0, stream>>>(o_buf, woutT, bout, attn_buf, 16384, 384, 256);
    gemm_bt<2><<<dim3(12, 128), b256, 0, stream>>>(f_buf, wff1T, bff1, ffh_buf, 16384, 1536, 384);
    gemm_bt<1><<<dim3(3, 128),  b256, 0, stream>>>(ffh_buf, wff2T, bff2, ffo_buf, 16384, 384, 1536);

    final_add<<<1536, b256, 0, stream>>>(x, attn_buf, ffo_buf, out);
}

// Round 3
// 286.968 us; speedup vs baseline: 1.1531x; 1.1531x over previous
//
#include <hip/hip_runtime.h>

typedef __bf16 bf16;
typedef __bf16 bf16x8 __attribute__((ext_vector_type(8)));
typedef float f32x4 __attribute__((ext_vector_type(4)));

__device__ __forceinline__ void gll16(const void* g, void* l) {
    __builtin_amdgcn_global_load_lds((const __attribute__((address_space(1))) void*)g,
                                     (__attribute__((address_space(3))) void*)l, 16, 0, 0);
}

// ---------------- weight transpose + fp32->bf16: in[R][C] f32 -> out[C][R] bf16 ----------------
__launch_bounds__(256)
__global__ void transpose_k(const float* __restrict__ in, bf16* __restrict__ out, int R, int Cc) {
    __shared__ float tl[32][33];
    const int c0 = blockIdx.x * 32, r0 = blockIdx.y * 32;
    const int cl = threadIdx.x & 31, r8 = threadIdx.x >> 5;
#pragma unroll
    for (int k = 0; k < 4; k++) {
        int r = k * 8 + r8;
        tl[r][cl] = in[(size_t)(r0 + r) * Cc + c0 + cl];
    }
    __syncthreads();
#pragma unroll
    for (int k = 0; k < 4; k++) {
        int cc = k * 8 + r8;
        out[(size_t)(c0 + cc) * R + r0 + cl] = (bf16)tl[cl][cc];
    }
}

// ---------------- dual LayerNorm: x[B,C,n] f32 -> a[B,n,C] bf16, f[B,n,C] bf16 ----------------
// LDS-transpose structure: load x tile [384 c][32 i] coalesced along i, stats from LDS,
// write rows with lane-consecutive c (contiguous 128B segments). Fixes R1's 3x write
// amplification (WRITE_SIZE 73MB -> 25MB expected).
__launch_bounds__(256)
__global__ void ln_kernel(const float* __restrict__ x,
                          const float* __restrict__ g1, const float* __restrict__ b1,
                          const float* __restrict__ g2, const float* __restrict__ b2,
                          bf16* __restrict__ a, bf16* __restrict__ f) {
    __shared__ float tile[384][33];
    __shared__ float S[8][32], SS[8][32], Mn[32], Rs[32];
    const int tid = threadIdx.x;
    const int bb = blockIdx.x >> 3;          // batch
    const int chunk = blockIdx.x & 7;        // 32-row chunk of n=256
    const int i0 = chunk * 32;

    // load phase: thread (c_l = tid>>5, i_l = tid&31); global reads coalesced along i
    {
        const int i_l = tid & 31, c_l = tid >> 5;
        const size_t base = (size_t)bb * 384 * 256 + i0 + i_l;
#pragma unroll 6
        for (int c = c_l; c < 384; c += 8)
            tile[c][i_l] = x[base + (size_t)c * 256];
    }
    __syncthreads();

    // stats phase: thread (p = tid>>5, i_s = tid&31) partial-sums 48 c's
    {
        const int i_s = tid & 31, p = tid >> 5;
        float s = 0.f, ss = 0.f;
#pragma unroll 6
        for (int j = 0; j < 48; j++) {
            float v = tile[p * 48 + j][i_s];
            s += v; ss += v * v;
        }
        S[p][i_s] = s; SS[p][i_s] = ss;
    }
    __syncthreads();
    if (tid < 32) {
        float t1 = 0.f, t2 = 0.f;
#pragma unroll
        for (int p = 0; p < 8; p++) { t1 += S[p][tid]; t2 += SS[p][tid]; }
        float mean = t1 * (1.0f / 384.0f);
        float var  = t2 * (1.0f / 384.0f) - mean * mean;
        Mn[tid] = mean;
        Rs[tid] = rsqrtf(var + 1e-5f);
    }
    __syncthreads();

    // write phase: wave w handles rows w*8..w*8+7; lanes cover contiguous c
    const int lane = tid & 63, w = tid >> 6;
#pragma unroll
    for (int rr = 0; rr < 8; rr++) {
        const int i = w * 8 + rr;
        const float mean = Mn[i], rstd = Rs[i];
        const size_t orow = ((size_t)bb * 256 + i0 + i) * 384;
#pragma unroll
        for (int pass = 0; pass < 6; pass++) {
            const int c = pass * 64 + lane;
            float nh = (tile[c][i] - mean) * rstd;
            a[orow + c] = (bf16)(nh * g1[c] + b1[c]);
            f[orow + c] = (bf16)(nh * g2[c] + b2[c]);
        }
    }
}

// ---------------- GEMM: C[M,N] = A[M,K] @ Bt[N,K]^T (+bias)(+gelu) ----------------
// 128x128 tile, BK=32, 4 waves, each wave 64x64 (4x4 MFMA 16x16x32 tiles).
// EPI: 0 = none, 1 = +bias, 2 = +bias +exact gelu. bias is fp32.
template <int EPI>
__launch_bounds__(256)
__global__ void gemm_bt(const bf16* __restrict__ A, const bf16* __restrict__ Bt,
                        const float* __restrict__ bias, bf16* __restrict__ C,
                        int M, int N, int K) {
    __shared__ bf16 lA[128 * 32];
    __shared__ bf16 lB[128 * 32];
    const int tid = threadIdx.x;
    const int m0 = blockIdx.y * 128;
    const int n0 = blockIdx.x * 128;
    const int lane = tid & 63, w = tid >> 6;
    const int l16 = lane & 15, quad = lane >> 4;
    const int wm = (w & 1) * 64, wn = (w >> 1) * 64;

    f32x4 zero = {0.f, 0.f, 0.f, 0.f};
    f32x4 acc[4][4];
#pragma unroll
    for (int i = 0; i < 4; i++)
#pragma unroll
        for (int j = 0; j < 4; j++) acc[i][j] = zero;

    const int c0 = tid, c1 = tid + 256;
    const int r0 = c0 >> 2, k0c = (c0 & 3) * 8;
    const int r1 = c1 >> 2, k1c = (c1 & 3) * 8;
    const bf16* Abase = A + (size_t)m0 * K;
    const bf16* Bbase = Bt + (size_t)n0 * K;

    for (int kb = 0; kb < K; kb += 32) {
        gll16(Abase + (size_t)r0 * K + kb + k0c, lA + c0 * 8);
        gll16(Abase + (size_t)r1 * K + kb + k1c, lA + c1 * 8);
        gll16(Bbase + (size_t)r0 * K + kb + k0c, lB + c0 * 8);
        gll16(Bbase + (size_t)r1 * K + kb + k1c, lB + c1 * 8);
        __syncthreads();
        bf16x8 af[4], bfr[4];
#pragma unroll
        for (int i = 0; i < 4; i++)
            af[i] = *(const bf16x8*)(lA + (wm + i * 16 + l16) * 32 + quad * 8);
#pragma unroll
        for (int j = 0; j < 4; j++)
            bfr[j] = *(const bf16x8*)(lB + (wn + j * 16 + l16) * 32 + quad * 8);
#pragma unroll
        for (int i = 0; i < 4; i++)
#pragma unroll
            for (int j = 0; j < 4; j++)
                acc[i][j] = __builtin_amdgcn_mfma_f32_16x16x32_bf16(af[i], bfr[j], acc[i][j], 0, 0, 0);
        __syncthreads();
    }

#pragma unroll
    for (int j = 0; j < 4; j++) {
        const int col = n0 + wn + j * 16 + l16;
        float bv = 0.f;
        if (EPI >= 1) bv = bias[col];
#pragma unroll
        for (int i = 0; i < 4; i++) {
            const int rowb = m0 + wm + i * 16 + quad * 4;
#pragma unroll
            for (int r = 0; r < 4; r++) {
                float v = acc[i][j][r] + bv;
                if (EPI == 2) v = 0.5f * v * (1.0f + erff(v * 0.70710678118654752f));
                C[(size_t)(rowb + r) * N + col] = (bf16)v;
            }
        }
    }
}

// ---------------- fused attention per (b, h, 64-row q-chunk) ----------------
// qkv[16384][768] bf16: q at col h*32, k at 256+h*32, v at 512+h*32. btab fp32 [961][8].
__launch_bounds__(256)
__global__ void attn_kernel(const bf16* __restrict__ qkv,
                            const float* __restrict__ btab,
                            bf16* __restrict__ o) {
    __shared__ float sbias[961];
    __shared__ __align__(16) bf16 sVt[32][264];      // Vt[d][k]
    __shared__ __align__(16) bf16 sP[4][16][264];    // per-wave P chunk [16 q][256 k]
    const int tid = threadIdx.x;
    const int qc = blockIdx.x & 3;
    const int h  = (blockIdx.x >> 2) & 7;
    const int bb = blockIdx.x >> 5;
    const int lane = tid & 63, w = tid >> 6;
    const int l16 = lane & 15, quad = lane >> 4;
    const size_t qkvb = (size_t)bb * 256 * 768;

    for (int e = tid; e < 961; e += 256) sbias[e] = btab[e * 8 + h];
#pragma unroll
    for (int it = 0; it < 32; it++) {
        int e = it * 256 + tid;
        int k = e >> 5, d = e & 31;
        sVt[d][k] = qkv[qkvb + (size_t)k * 768 + 512 + h * 32 + d];
    }
    __syncthreads();

    const int qbase = qc * 64 + w * 16;
    bf16x8 qf = *(const bf16x8*)(qkv + qkvb + (size_t)(qbase + l16) * 768 + h * 32 + quad * 8);
    f32x4 zero = {0.f, 0.f, 0.f, 0.f};
    f32x4 s[16];
#pragma unroll
    for (int kt = 0; kt < 16; kt++) {
        bf16x8 kf = *(const bf16x8*)(qkv + qkvb + (size_t)(kt * 16 + l16) * 768 + 256 + h * 32 + quad * 8);
        s[kt] = __builtin_amdgcn_mfma_f32_16x16x32_bf16(qf, kf, zero, 0, 0, 0);
    }
    const int qi0 = qbase + quad * 4;
    float mx[4] = {-1e30f, -1e30f, -1e30f, -1e30f};
#pragma unroll
    for (int kt = 0; kt < 16; kt++) {
        const int j = kt * 16 + l16;
        const int yj = j >> 4, xj = j & 15;
#pragma unroll
        for (int r = 0; r < 4; r++) {
            const int q = qi0 + r;
            const int tix = ((q >> 4) - yj + 15) * 31 + ((q & 15) - xj + 15);
            float v = s[kt][r] * 0.17677669529663687f + sbias[tix];
            s[kt][r] = v;
            mx[r] = fmaxf(mx[r], v);
        }
    }
#pragma unroll
    for (int r = 0; r < 4; r++)
        for (int msk = 1; msk < 16; msk <<= 1)
            mx[r] = fmaxf(mx[r], __shfl_xor(mx[r], msk, 64));
    float sum[4] = {0.f, 0.f, 0.f, 0.f};
#pragma unroll
    for (int kt = 0; kt < 16; kt++)
#pragma unroll
        for (int r = 0; r < 4; r++) {
            float e = __expf(s[kt][r] - mx[r]);
            s[kt][r] = e;
            sum[r] += e;
        }
#pragma unroll
    for (int r = 0; r < 4; r++) {
        for (int msk = 1; msk < 16; msk <<= 1)
            sum[r] += __shfl_xor(sum[r], msk, 64);
        sum[r] = 1.0f / sum[r];
    }
#pragma unroll
    for (int kt = 0; kt < 16; kt++)
#pragma unroll
        for (int r = 0; r < 4; r++)
            sP[w][quad * 4 + r][kt * 16 + l16] = (bf16)(s[kt][r] * sum[r]);
    f32x4 oacc[2];
    oacc[0] = zero; oacc[1] = zero;
#pragma unroll
    for (int ks = 0; ks < 8; ks++) {
        bf16x8 pf = *(const bf16x8*)(&sP[w][l16][ks * 32 + quad * 8]);
#pragma unroll
        for (int dt = 0; dt < 2; dt++) {
            bf16x8 vf = *(const bf16x8*)(&sVt[dt * 16 + l16][ks * 32 + quad * 8]);
            oacc[dt] = __builtin_amdgcn_mfma_f32_16x16x32_bf16(pf, vf, oacc[dt], 0, 0, 0);
        }
    }
#pragma unroll
    for (int dt = 0; dt < 2; dt++)
#pragma unroll
        for (int r = 0; r < 4; r++)
            o[(size_t)(bb * 256 + qbase + quad * 4 + r) * 256 + h * 32 + dt * 16 + l16] = (bf16)oacc[dt][r];
}

// ---------------- final: out[b,c,i] = x[b,c,i] + attn[b,i,c] + ffo[b,i,c] (fp32 out) ---------
__launch_bounds__(256)
__global__ void final_add(const float* __restrict__ x, const bf16* __restrict__ attn,
                          const bf16* __restrict__ ffo, float* __restrict__ out) {
    __shared__ float tile[64][65];
    const int tid = threadIdx.x;
    const int i0 = (blockIdx.x & 3) * 64;
    const int c0 = ((blockIdx.x >> 2) % 6) * 64;
    const int bb = blockIdx.x / 24;
    const int cl = tid & 63, i8 = tid >> 6;
#pragma unroll
    for (int k = 0; k < 16; k++) {
        int il = k * 4 + i8;
        size_t addr = ((size_t)(bb * 256 + i0 + il)) * 384 + c0 + cl;
        tile[il][cl] = (float)attn[addr] + (float)ffo[addr];
    }
    __syncthreads();
    const int il2 = tid & 63, c8 = tid >> 6;
#pragma unroll
    for (int k = 0; k < 16; k++) {
        int cl2 = k * 4 + c8;
        size_t addr = ((size_t)(bb * 384 + c0 + cl2)) * 256 + i0 + il2;
        out[addr] = x[addr] + tile[il2][cl2];
    }
}

extern "C" void kernel_launch(void* const* d_in, const int* in_sizes, int n_in,
                              void* d_out, int out_size, void* d_ws, size_t ws_size,
                              hipStream_t stream) {
    const float* x    = (const float*)d_in[0];
    const float* g1   = (const float*)d_in[1];
    const float* b1   = (const float*)d_in[2];
    const float* wqkv = (const float*)d_in[3];
    const float* btab = (const float*)d_in[4];
    const float* wout = (const float*)d_in[5];
    const float* bout = (const float*)d_in[6];
    const float* g2   = (const float*)d_in[7];
    const float* b2   = (const float*)d_in[8];
    const float* wff1 = (const float*)d_in[9];
    const float* bff1 = (const float*)d_in[10];
    const float* wff2 = (const float*)d_in[11];
    const float* bff2 = (const float*)d_in[12];
    float* out = (float*)d_out;

    bf16* ws = (bf16*)d_ws;
    const size_t NA = 6291456;                 // 16384*384
    bf16* wqkvT = ws;                          // [768,384]
    bf16* woutT = wqkvT + 294912;              // [384,256]
    bf16* wff1T = woutT + 98304;               // [1536,384]
    bf16* wff2T = wff1T + 589824;              // [384,1536]
    bf16* f_buf    = ws + 1572864;             // [16384,384]
    bf16* attn_buf = f_buf + NA;               // [16384,384]
    bf16* ffo_buf  = attn_buf + NA;            // [16384,384]
    bf16* R        = ffo_buf + NA;             // reuse region
    bf16* a_buf    = R;                        // [16384,384]   live ln -> qkvgemm
    bf16* qkv_buf  = R + NA;                   // [16384,768]   live qkvgemm -> attn
    bf16* o_buf    = R;                        // [16384,256]   live attn -> outproj
    bf16* ffh_buf  = R;                        // [16384,1536]  live ff1 -> ff2

    dim3 b256(256);
    transpose_k<<<dim3(24, 12), b256, 0, stream>>>(wqkv, wqkvT, 384, 768);
    transpose_k<<<dim3(12, 8),  b256, 0, stream>>>(wout, woutT, 256, 384);
    transpose_k<<<dim3(48, 12), b256, 0, stream>>>(wff1, wff1T, 384, 1536);
    transpose_k<<<dim3(12, 48), b256, 0, stream>>>(wff2, wff2T, 1536, 384);

    ln_kernel<<<512, b256, 0, stream>>>(x, g1, b1, g2, b2, a_buf, f_buf);

    gemm_bt<0><<<dim3(6, 128),  b256, 0, stream>>>(a_buf, wqkvT, nullptr, qkv_buf, 16384, 768, 384);
    attn_kernel<<<2048, b256, 0, stream>>>(qkv_buf, btab, o_buf);
    gemm_bt<1><<<dim3(3, 128),  b256, 0, stream>>>(o_buf, woutT, bout, attn_buf, 16384, 384, 256);
    gemm_bt<2><<<dim3(12, 128), b256, 0, stream>>>(f_buf, wff1T, bff1, ffh_buf, 16384, 1536, 384);
    gemm_bt<1><<<dim3(3, 128),  b256, 0, stream>>>(ffh_buf, wff2T, bff2, ffo_buf, 16384, 384, 1536);

    final_add<<<1536, b256, 0, stream>>>(x, attn_buf, ffo_buf, out);
}

// Round 4
// 275.398 us; speedup vs baseline: 1.2016x; 1.0420x over previous
//
#include <hip/hip_runtime.h>

typedef __bf16 bf16;
typedef __bf16 bf16x8 __attribute__((ext_vector_type(8)));
typedef float f32x4 __attribute__((ext_vector_type(4)));

__device__ __forceinline__ void gll16(const void* g, void* l) {
    __builtin_amdgcn_global_load_lds((const __attribute__((address_space(1))) void*)g,
                                     (__attribute__((address_space(3))) void*)l, 16, 0, 0);
}

// ---------------- weight transpose + fp32->bf16: in[R][C] f32 -> out[C][R] bf16 ----------------
__launch_bounds__(256)
__global__ void transpose_k(const float* __restrict__ in, bf16* __restrict__ out, int R, int Cc) {
    __shared__ float tl[32][33];
    const int c0 = blockIdx.x * 32, r0 = blockIdx.y * 32;
    const int cl = threadIdx.x & 31, r8 = threadIdx.x >> 5;
#pragma unroll
    for (int k = 0; k < 4; k++) {
        int r = k * 8 + r8;
        tl[r][cl] = in[(size_t)(r0 + r) * Cc + c0 + cl];
    }
    __syncthreads();
#pragma unroll
    for (int k = 0; k < 4; k++) {
        int cc = k * 8 + r8;
        out[(size_t)(c0 + cc) * R + r0 + cl] = (bf16)tl[cl][cc];
    }
}

// ---------------- dual LayerNorm: x[B,C,n] f32 -> a[B,n,C] bf16, f[B,n,C] bf16 ----------------
__launch_bounds__(256)
__global__ void ln_kernel(const float* __restrict__ x,
                          const float* __restrict__ g1, const float* __restrict__ b1,
                          const float* __restrict__ g2, const float* __restrict__ b2,
                          bf16* __restrict__ a, bf16* __restrict__ f) {
    __shared__ float tile[384][33];
    __shared__ float S[8][32], SS[8][32], Mn[32], Rs[32];
    const int tid = threadIdx.x;
    const int bb = blockIdx.x >> 3;
    const int chunk = blockIdx.x & 7;
    const int i0 = chunk * 32;
    {
        const int i_l = tid & 31, c_l = tid >> 5;
        const size_t base = (size_t)bb * 384 * 256 + i0 + i_l;
#pragma unroll 6
        for (int c = c_l; c < 384; c += 8)
            tile[c][i_l] = x[base + (size_t)c * 256];
    }
    __syncthreads();
    {
        const int i_s = tid & 31, p = tid >> 5;
        float s = 0.f, ss = 0.f;
#pragma unroll 6
        for (int j = 0; j < 48; j++) {
            float v = tile[p * 48 + j][i_s];
            s += v; ss += v * v;
        }
        S[p][i_s] = s; SS[p][i_s] = ss;
    }
    __syncthreads();
    if (tid < 32) {
        float t1 = 0.f, t2 = 0.f;
#pragma unroll
        for (int p = 0; p < 8; p++) { t1 += S[p][tid]; t2 += SS[p][tid]; }
        float mean = t1 * (1.0f / 384.0f);
        float var  = t2 * (1.0f / 384.0f) - mean * mean;
        Mn[tid] = mean;
        Rs[tid] = rsqrtf(var + 1e-5f);
    }
    __syncthreads();
    const int lane = tid & 63, w = tid >> 6;
#pragma unroll
    for (int rr = 0; rr < 8; rr++) {
        const int i = w * 8 + rr;
        const float mean = Mn[i], rstd = Rs[i];
        const size_t orow = ((size_t)bb * 256 + i0 + i) * 384;
#pragma unroll
        for (int pass = 0; pass < 6; pass++) {
            const int c = pass * 64 + lane;
            float nh = (tile[c][i] - mean) * rstd;
            a[orow + c] = (bf16)(nh * g1[c] + b1[c]);
            f[orow + c] = (bf16)(nh * g2[c] + b2[c]);
        }
    }
}

// ---------------- GEMM: C[M,N] = A[M,K] @ Bt[N,K]^T (+bias)(+gelu) ----------------
// 128x128 tile, BK=64, XOR-swizzled LDS (conflict-free ds_read_b128, swizzle applied on
// the global source address so global_load_lds lane-contiguous dest still works),
// LDS-staged epilogue with dwordx4 stores (kills partial-line write amplification).
// 1-D grid with XCD swizzle: all column-blocks of a row-strip land on one XCD.
template <int EPI>
__launch_bounds__(256)
__global__ void gemm_bt(const bf16* __restrict__ A, const bf16* __restrict__ Bt,
                        const float* __restrict__ bias, bf16* __restrict__ C,
                        int M, int N, int K, int nx) {
    __shared__ bf16 lds[16384];          // 32 KB: lA [0,8192), lB [8192,16384)
    bf16* lA = lds;
    bf16* lB = lds + 8192;
    const int tid = threadIdx.x;
    const int g = blockIdx.x;
    const int x = (g >> 3) % nx;
    const int y = (g & 7) + 8 * (g / (8 * nx));
    const int m0 = y * 128, n0 = x * 128;
    const int lane = tid & 63, w = tid >> 6;
    const int l16 = lane & 15, quad = lane >> 4;
    const int wm = (w & 1) * 64, wn = (w >> 1) * 64;

    f32x4 zero = {0.f, 0.f, 0.f, 0.f};
    f32x4 acc[4][4];
#pragma unroll
    for (int i = 0; i < 4; i++)
#pragma unroll
        for (int j = 0; j < 4; j++) acc[i][j] = zero;

    // staging: 1024 chunks of 16B per matrix per iter; thread handles chunks tid+256*i.
    // chunk -> (row = chunk>>3, phys = chunk&7); source logical chunk = phys ^ (row&7).
    const int rb = tid >> 3;                               // row base 0..31 (+32*i)
    const int cs = ((tid & 7) ^ (rb & 7)) << 3;            // logical chunk elem offset
    const bf16* Ab = A + (size_t)(m0 + rb) * K + cs;
    const bf16* Bb = Bt + (size_t)(n0 + rb) * K + cs;
    bf16* la_dst = lA + tid * 8;
    bf16* lb_dst = lB + tid * 8;
    const int swz = l16 & 7;                               // fragment-read swizzle

    for (int kb = 0; kb < K; kb += 64) {
#pragma unroll
        for (int i = 0; i < 4; i++)
            gll16(Ab + (size_t)(32 * i) * K + kb, la_dst + i * 2048);
#pragma unroll
        for (int i = 0; i < 4; i++)
            gll16(Bb + (size_t)(32 * i) * K + kb, lb_dst + i * 2048);
        __syncthreads();
        bf16x8 af[2][4], bfr[2][4];
#pragma unroll
        for (int s = 0; s < 2; s++) {
            const int lc = quad + 4 * s;
            const int pc = (lc ^ swz) << 3;
#pragma unroll
            for (int i = 0; i < 4; i++) {
                af[s][i]  = *(const bf16x8*)(lA + (wm + i * 16 + l16) * 64 + pc);
                bfr[s][i] = *(const bf16x8*)(lB + (wn + i * 16 + l16) * 64 + pc);
            }
        }
#pragma unroll
        for (int s = 0; s < 2; s++)
#pragma unroll
            for (int i = 0; i < 4; i++)
#pragma unroll
                for (int j = 0; j < 4; j++)
                    acc[i][j] = __builtin_amdgcn_mfma_f32_16x16x32_bf16(af[s][i], bfr[s][j], acc[i][j], 0, 0, 0);
        __syncthreads();
    }

    // epilogue: acc -> LDS C-tile (bf16, [128][128]) -> coalesced dwordx4 stores
#pragma unroll
    for (int j = 0; j < 4; j++) {
        const int col = wn + j * 16 + l16;
        float bv = 0.f;
        if (EPI >= 1) bv = bias[n0 + col];
#pragma unroll
        for (int i = 0; i < 4; i++) {
            const int row0 = wm + i * 16 + quad * 4;
#pragma unroll
            for (int r = 0; r < 4; r++) {
                float v = acc[i][j][r] + bv;
                if (EPI == 2) v = 0.5f * v * (1.0f + erff(v * 0.70710678118654752f));
                lds[(row0 + r) * 128 + col] = (bf16)v;
            }
        }
    }
    __syncthreads();
#pragma unroll
    for (int it = 0; it < 8; it++) {
        const int ch = tid + it * 256;
        const int row = ch >> 4, cc = (ch & 15) * 8;
        *(bf16x8*)(C + (size_t)(m0 + row) * N + n0 + cc) = *(const bf16x8*)(lds + row * 128 + cc);
    }
}

// ---------------- fused attention per (b, h, 64-row q-chunk) ----------------
__launch_bounds__(256)
__global__ void attn_kernel(const bf16* __restrict__ qkv,
                            const float* __restrict__ btab,
                            bf16* __restrict__ o) {
    __shared__ float sbias[961];
    __shared__ __align__(16) bf16 sVt[32][264];
    __shared__ __align__(16) bf16 sP[4][16][264];
    const int tid = threadIdx.x;
    const int qc = blockIdx.x & 3;
    const int h  = (blockIdx.x >> 2) & 7;
    const int bb = blockIdx.x >> 5;
    const int lane = tid & 63, w = tid >> 6;
    const int l16 = lane & 15, quad = lane >> 4;
    const size_t qkvb = (size_t)bb * 256 * 768;

    for (int e = tid; e < 961; e += 256) sbias[e] = btab[e * 8 + h];
#pragma unroll
    for (int it = 0; it < 32; it++) {
        int e = it * 256 + tid;
        int k = e >> 5, d = e & 31;
        sVt[d][k] = qkv[qkvb + (size_t)k * 768 + 512 + h * 32 + d];
    }
    __syncthreads();

    const int qbase = qc * 64 + w * 16;
    bf16x8 qf = *(const bf16x8*)(qkv + qkvb + (size_t)(qbase + l16) * 768 + h * 32 + quad * 8);
    f32x4 zero = {0.f, 0.f, 0.f, 0.f};
    f32x4 s[16];
#pragma unroll
    for (int kt = 0; kt < 16; kt++) {
        bf16x8 kf = *(const bf16x8*)(qkv + qkvb + (size_t)(kt * 16 + l16) * 768 + 256 + h * 32 + quad * 8);
        s[kt] = __builtin_amdgcn_mfma_f32_16x16x32_bf16(qf, kf, zero, 0, 0, 0);
    }
    const int qi0 = qbase + quad * 4;
    float mx[4] = {-1e30f, -1e30f, -1e30f, -1e30f};
#pragma unroll
    for (int kt = 0; kt < 16; kt++) {
        const int j = kt * 16 + l16;
        const int yj = j >> 4, xj = j & 15;
#pragma unroll
        for (int r = 0; r < 4; r++) {
            const int q = qi0 + r;
            const int tix = ((q >> 4) - yj + 15) * 31 + ((q & 15) - xj + 15);
            float v = s[kt][r] * 0.17677669529663687f + sbias[tix];
            s[kt][r] = v;
            mx[r] = fmaxf(mx[r], v);
        }
    }
#pragma unroll
    for (int r = 0; r < 4; r++)
        for (int msk = 1; msk < 16; msk <<= 1)
            mx[r] = fmaxf(mx[r], __shfl_xor(mx[r], msk, 64));
    float sum[4] = {0.f, 0.f, 0.f, 0.f};
#pragma unroll
    for (int kt = 0; kt < 16; kt++)
#pragma unroll
        for (int r = 0; r < 4; r++) {
            float e = __expf(s[kt][r] - mx[r]);
            s[kt][r] = e;
            sum[r] += e;
        }
#pragma unroll
    for (int r = 0; r < 4; r++) {
        for (int msk = 1; msk < 16; msk <<= 1)
            sum[r] += __shfl_xor(sum[r], msk, 64);
        sum[r] = 1.0f / sum[r];
    }
#pragma unroll
    for (int kt = 0; kt < 16; kt++)
#pragma unroll
        for (int r = 0; r < 4; r++)
            sP[w][quad * 4 + r][kt * 16 + l16] = (bf16)(s[kt][r] * sum[r]);
    f32x4 oacc[2];
    oacc[0] = zero; oacc[1] = zero;
#pragma unroll
    for (int ks = 0; ks < 8; ks++) {
        bf16x8 pf = *(const bf16x8*)(&sP[w][l16][ks * 32 + quad * 8]);
#pragma unroll
        for (int dt = 0; dt < 2; dt++) {
            bf16x8 vf = *(const bf16x8*)(&sVt[dt * 16 + l16][ks * 32 + quad * 8]);
            oacc[dt] = __builtin_amdgcn_mfma_f32_16x16x32_bf16(pf, vf, oacc[dt], 0, 0, 0);
        }
    }
#pragma unroll
    for (int dt = 0; dt < 2; dt++)
#pragma unroll
        for (int r = 0; r < 4; r++)
            o[(size_t)(bb * 256 + qbase + quad * 4 + r) * 256 + h * 32 + dt * 16 + l16] = (bf16)oacc[dt][r];
}

// ---------------- final: out[b,c,i] = x[b,c,i] + attn[b,i,c] + ffo[b,i,c] (fp32 out) ---------
__launch_bounds__(256)
__global__ void final_add(const float* __restrict__ x, const bf16* __restrict__ attn,
                          const bf16* __restrict__ ffo, float* __restrict__ out) {
    __shared__ float tile[64][65];
    const int tid = threadIdx.x;
    const int i0 = (blockIdx.x & 3) * 64;
    const int c0 = ((blockIdx.x >> 2) % 6) * 64;
    const int bb = blockIdx.x / 24;
    const int cl = tid & 63, i8 = tid >> 6;
#pragma unroll
    for (int k = 0; k < 16; k++) {
        int il = k * 4 + i8;
        size_t addr = ((size_t)(bb * 256 + i0 + il)) * 384 + c0 + cl;
        tile[il][cl] = (float)attn[addr] + (float)ffo[addr];
    }
    __syncthreads();
    const int il2 = tid & 63, c8 = tid >> 6;
#pragma unroll
    for (int k = 0; k < 16; k++) {
        int cl2 = k * 4 + c8;
        size_t addr = ((size_t)(bb * 384 + c0 + cl2)) * 256 + i0 + il2;
        out[addr] = x[addr] + tile[il2][cl2];
    }
}

extern "C" void kernel_launch(void* const* d_in, const int* in_sizes, int n_in,
                              void* d_out, int out_size, void* d_ws, size_t ws_size,
                              hipStream_t stream) {
    const float* x    = (const float*)d_in[0];
    const float* g1   = (const float*)d_in[1];
    const float* b1   = (const float*)d_in[2];
    const float* wqkv = (const float*)d_in[3];
    const float* btab = (const float*)d_in[4];
    const float* wout = (const float*)d_in[5];
    const float* bout = (const float*)d_in[6];
    const float* g2   = (const float*)d_in[7];
    const float* b2   = (const float*)d_in[8];
    const float* wff1 = (const float*)d_in[9];
    const float* bff1 = (const float*)d_in[10];
    const float* wff2 = (const float*)d_in[11];
    const float* bff2 = (const float*)d_in[12];
    float* out = (float*)d_out;

    bf16* ws = (bf16*)d_ws;
    const size_t NA = 6291456;                 // 16384*384
    bf16* wqkvT = ws;                          // [768,384]
    bf16* woutT = wqkvT + 294912;              // [384,256]
    bf16* wff1T = woutT + 98304;               // [1536,384]
    bf16* wff2T = wff1T + 589824;              // [384,1536]
    bf16* f_buf    = ws + 1572864;             // [16384,384]
    bf16* attn_buf = f_buf + NA;               // [16384,384]
    bf16* ffo_buf  = attn_buf + NA;            // [16384,384]
    bf16* R        = ffo_buf + NA;             // reuse region
    bf16* a_buf    = R;                        // [16384,384]   live ln -> qkvgemm
    bf16* qkv_buf  = R + NA;                   // [16384,768]   live qkvgemm -> attn
    bf16* o_buf    = R;                        // [16384,256]   live attn -> outproj
    bf16* ffh_buf  = R;                        // [16384,1536]  live ff1 -> ff2

    dim3 b256(256);
    transpose_k<<<dim3(24, 12), b256, 0, stream>>>(wqkv, wqkvT, 384, 768);
    transpose_k<<<dim3(12, 8),  b256, 0, stream>>>(wout, woutT, 256, 384);
    transpose_k<<<dim3(48, 12), b256, 0, stream>>>(wff1, wff1T, 384, 1536);
    transpose_k<<<dim3(12, 48), b256, 0, stream>>>(wff2, wff2T, 1536, 384);

    ln_kernel<<<512, b256, 0, stream>>>(x, g1, b1, g2, b2, a_buf, f_buf);

    gemm_bt<0><<<6 * 128,  b256, 0, stream>>>(a_buf, wqkvT, nullptr, qkv_buf, 16384, 768, 384, 6);
    attn_kernel<<<2048, b256, 0, stream>>>(qkv_buf, btab, o_buf);
    gemm_bt<1><<<3 * 128,  b256, 0, stream>>>(o_buf, woutT, bout, attn_buf, 16384, 384, 256, 3);
    gemm_bt<2><<<12 * 128, b256, 0, stream>>>(f_buf, wff1T, bff1, ffh_buf, 16384, 1536, 384, 12);
    gemm_bt<1><<<3 * 128,  b256, 0, stream>>>(ffh_buf, wff2T, bff2, ffo_buf, 16384, 384, 1536, 3);

    final_add<<<1536, b256, 0, stream>>>(x, attn_buf, ffo_buf, out);
}